// Round 13
// baseline (89.247 us; speedup 1.0000x reference)
//
#include <hip/hip_runtime.h>

#define NB_BS   2048
#define NB_NINP 512
#define NB_NHID 512
#define NB_K    16
#define NB_T    8
#define NB_M    32
#define NB_C    768   // T * 3 * M
#define H_OUT_ELEMS (NB_BS * NB_NHID)   // 1048576

// ---------------------------------------------------------------------------
// Kernel 1 (r11 verbatim -- best measured total): 64x96 tile, 1024 threads,
// K-SPLIT-4 inside the block (kg = tid>>8 owns K-quarter), 4x6 micro with
// 4-addr broadcast av + conflict-free 3x b64 wv. Grid (32,8) = 256 = 1/CU.
// Partials combine through one reused ACCX buffer, 3 rounds.
// ---------------------------------------------------------------------------
__global__ __launch_bounds__(1024)
void k1_gemm_gi(const float* __restrict__ x, const float* __restrict__ Wih,
                const float* __restrict__ bih, const float* __restrict__ bhh,
                float* __restrict__ gi)
{
    __shared__ __align__(16) float As[4][16][68];    // [kg][k][row] 17.4 KB
    __shared__ __align__(16) float Bs[4][16][100];   // [kg][k][col] 25.6 KB
    __shared__ float ACCX[256][25];                  // 25.6 KB (25 coprime 32)

    const int tid  = threadIdx.x;
    const int kg   = tid >> 8;            // K-quarter
    const int ttid = tid & 255;
    const int row0 = blockIdx.x * 64;
    const int col0 = blockIdx.y * 96;
    const int rg   = ttid >> 4;           // 0..15 -> rows rg*4..+3 (4/wave)
    const int cg   = ttid & 15;           // 0..15 -> cols cg*6..+5
    const int kb0  = kg * 128;

    const int ar = ttid >> 2, akq = (ttid & 3) * 4;
    const int bc0 = ttid >> 2,         bk0 = (ttid & 3) * 4;
    const int bc1 = (256 + ttid) >> 2, bk1 = (ttid & 3) * 4;   // ttid<128 only

    float4 a0 = *(const float4*)&x[(size_t)(row0 + ar) * NB_NINP + kb0 + akq];
    float4 b0 = *(const float4*)&Wih[(size_t)(col0 + bc0) * NB_NINP + kb0 + bk0];
    float4 b1;
    if (ttid < 128)
        b1 = *(const float4*)&Wih[(size_t)(col0 + bc1) * NB_NINP + kb0 + bk1];

    float acc[4][6];
    #pragma unroll
    for (int i = 0; i < 4; ++i)
        #pragma unroll
        for (int e = 0; e < 6; ++e) acc[i][e] = 0.f;

    for (int slab = 0; slab < 8; ++slab) {           // 8 slabs of BK=16
        __syncthreads();
        As[kg][akq+0][ar]=a0.x; As[kg][akq+1][ar]=a0.y;
        As[kg][akq+2][ar]=a0.z; As[kg][akq+3][ar]=a0.w;
        Bs[kg][bk0+0][bc0]=b0.x; Bs[kg][bk0+1][bc0]=b0.y;
        Bs[kg][bk0+2][bc0]=b0.z; Bs[kg][bk0+3][bc0]=b0.w;
        if (ttid < 128) {
            Bs[kg][bk1+0][bc1]=b1.x; Bs[kg][bk1+1][bc1]=b1.y;
            Bs[kg][bk1+2][bc1]=b1.z; Bs[kg][bk1+3][bc1]=b1.w;
        }
        __syncthreads();
        if (slab < 7) {   // prefetch next slab of this K-quarter
            const int kb = kb0 + (slab + 1) * 16;
            a0 = *(const float4*)&x[(size_t)(row0 + ar) * NB_NINP + kb + akq];
            b0 = *(const float4*)&Wih[(size_t)(col0 + bc0) * NB_NINP + kb + bk0];
            if (ttid < 128)
                b1 = *(const float4*)&Wih[(size_t)(col0 + bc1) * NB_NINP + kb + bk1];
        }
        #pragma unroll
        for (int kk = 0; kk < 16; ++kk) {
            const float4 av = *(const float4*)&As[kg][kk][rg * 4];   // 4-addr bc
            const float2 w0 = *(const float2*)&Bs[kg][kk][cg * 6];
            const float2 w1 = *(const float2*)&Bs[kg][kk][cg * 6 + 2];
            const float2 w2 = *(const float2*)&Bs[kg][kk][cg * 6 + 4];
            const float avv[4] = {av.x, av.y, av.z, av.w};
            const float wvv[6] = {w0.x, w0.y, w1.x, w1.y, w2.x, w2.y};
            #pragma unroll
            for (int i = 0; i < 4; ++i)
                #pragma unroll
                for (int e = 0; e < 6; ++e)
                    acc[i][e] = fmaf(avv[i], wvv[e], acc[i][e]);
        }
    }

    #pragma unroll 1
    for (int src = 1; src < 4; ++src) {
        __syncthreads();
        if (kg == src) {
            #pragma unroll
            for (int i = 0; i < 4; ++i)
                #pragma unroll
                for (int e = 0; e < 6; ++e) ACCX[ttid][i * 6 + e] = acc[i][e];
        }
        __syncthreads();
        if (kg == 0) {
            #pragma unroll
            for (int i = 0; i < 4; ++i)
                #pragma unroll
                for (int e = 0; e < 6; ++e) acc[i][e] += ACCX[ttid][i * 6 + e];
        }
    }
    if (kg == 0) {                        // bias + store
        float bias[6];
        #pragma unroll
        for (int e = 0; e < 6; ++e) {
            const int cl = cg * 6 + e;    // c % 96
            const int c  = col0 + cl;
            bias[e] = bih[c] + (cl < 64 ? bhh[c] : 0.f);
        }
        #pragma unroll
        for (int i = 0; i < 4; ++i) {
            const size_t base = (size_t)(row0 + rg * 4 + i) * NB_C + col0 + cg * 6;
            #pragma unroll
            for (int e = 0; e < 6; e += 2) {
                float2 o;
                o.x = acc[i][e]   + bias[e];
                o.y = acc[i][e+1] + bias[e+1];
                *(float2*)&gi[base + e] = o;
            }
        }
    }
}

// ---------------------------------------------------------------------------
// Kernel 2: r11/r10 structure (best: 50.4us / 60 VGPR / no spill), with the
// P and WWT4 staging rewritten SLOT-MAJOR: each thread gathers the 4
// components of one float4 slot from L2-hot Whh/wwrite and writes it as a
// single conflict-free ds_write_b128 at consecutive slots (was 24 coalesced
// loads + 24 4-way-conflicted b32 scatter writes; SQ_LDS_BANK_CONFLICT
// 1.39M ~= 2.3us of the 50). Compute loops identical to r11.
// ---------------------------------------------------------------------------
__global__ __launch_bounds__(1024)
__attribute__((amdgpu_waves_per_eu(4, 4)))
void k2_fused(const float* __restrict__ h,      const float* __restrict__ Whh,
              const float* __restrict__ bhh,    const float* __restrict__ wread,
              const float* __restrict__ wwrite, const float* __restrict__ gumb,
              const float* __restrict__ gi,     float* __restrict__ out)
{
    __shared__ __align__(16) float4 P[3][32][64];   // 98304 B  W_hh planes
    __shared__ __align__(16) float4 WWT4[16][64];   // 16384 B  [f][t1*32+m]:p-quad
    __shared__ __align__(16) float WR[512];         //  2048 B  w_read [m][f]
    __shared__ __align__(16) float HT[8][32][20];   // 20480 B  [bl][m][k]
    __shared__ __align__(16) float HR2T[8][16][20]; // 10240 B  [bl][f][k]
    __shared__ __align__(16) float LG[8][16][8];    //  4096 B  [bl][k][t]

    const int tid  = threadIdx.x;
    const int wave = tid >> 6, lane = tid & 63;
    const int bl   = wave >> 1, kh = wave & 1;
    const int b    = blockIdx.x * 8 + bl;
    const int m_   = lane & 31, half = lane >> 5;

    // ---- stage W_hh planes, slot-major: slot (jq, mm, sl) holds, in
    //      component jj, Whh value for j = jq*4+jj = (t>>1)*3+gc, with
    //      t&1 and mout decoded from sl^(mm&7). Consecutive lanes ->
    //      consecutive sl -> conflict-free b128 writes.
    #pragma unroll 2
    for (int s = tid; s < 6144; s += 1024) {
        const int jq = s >> 11;            // 0..2
        const int mm = (s >> 6) & 31;
        const int sl = s & 63;
        const int un = sl ^ (mm & 7);      // (t&1)*32 + mout
        const int t1 = un >> 5, mout = un & 31;
        float v[4];
        #pragma unroll
        for (int jj = 0; jj < 4; ++jj) {
            const int q  = jq * 4 + jj;    // (t>>1)*3 + gc
            const int tt = q / 3, gc = q - tt * 3;
            const int t  = tt * 2 + t1;
            v[jj] = Whh[(t * 96 + gc * 32 + mout) * 32 + mm];
        }
        P[jq][mm][sl] = make_float4(v[0], v[1], v[2], v[3]);
    }
    {   // WWT4 slot-major: slot (f, t1*32+mo) holds component p = t>>1
        const int s = tid & 1023;          // 1024 slots, 1024 threads
        const int f = s >> 6, t1 = (s >> 5) & 1, mo = s & 31;
        float v[4];
        #pragma unroll
        for (int p = 0; p < 4; ++p)
            v[p] = wwrite[(p * 2 + t1) * 512 + mo * 16 + f];
        WWT4[f][t1 * 32 + mo] = make_float4(v[0], v[1], v[2], v[3]);
    }
    if (tid < 512) WR[tid] = wread[tid];
    #pragma unroll
    for (int e = 0; e < 4; ++e) {                   // this wave's h half-row, transposed
        const int idx = kh * 256 + e * 64 + lane;
        HT[bl][idx & 31][idx >> 5] = h[(size_t)b * NB_NHID + idx];
    }
    __syncthreads();   // only barrier; everything below is wave-local

    // ---- h_read for this wave's 8 k's: lane owns (k = kh*8 + lane>>3, f-pair)
    {
        const int kq = kh * 8 + (lane >> 3);
        const int f0 = (lane & 7) * 2;
        float s0 = 0.f, s1 = 0.f;
        #pragma unroll 8
        for (int mm = 0; mm < 32; ++mm) {
            const float hv = HT[bl][mm][kq];
            s0 = fmaf(hv, WR[mm * 16 + f0], s0);
            s1 = fmaf(hv, WR[mm * 16 + f0 + 1], s1);
        }
        HR2T[bl][f0    ][kq] = s0;
        HR2T[bl][f0 + 1][kq] = s1;
    }

    // ---- per-lane gi' (bih+bhh_{r,z} folded by k1) and bhh_n
    float gi_r[4][3], bhn[4];
    #pragma unroll
    for (int p = 0; p < 4; ++p) {
        const int t = 2 * p + half;
        #pragma unroll
        for (int gc = 0; gc < 3; ++gc)
            gi_r[p][gc] = gi[(size_t)b * NB_C + t * 96 + gc * 32 + m_];
        bhn[p] = bhh[t * 96 + 64 + m_];
    }

    #pragma unroll 1
    for (int pass = 0; pass < 2; ++pass) {
        const int k0 = kh * 8 + pass * 4;

        // ---- gh GEMM, 4 k's: 48 FMA per mm; 3 spread b128 + 1 broadcast b128
        float acc[4][12];
        #pragma unroll
        for (int r = 0; r < 4; ++r)
            #pragma unroll
            for (int j = 0; j < 12; ++j) acc[r][j] = 0.f;

        __builtin_amdgcn_s_setprio(1);
        #pragma unroll 4
        for (int mm = 0; mm < 32; ++mm) {
            const int sw = lane ^ (mm & 7);          // undo staging swizzle
            const float4 w0 = P[0][mm][sw];
            const float4 w1 = P[1][mm][sw];
            const float4 w2 = P[2][mm][sw];
            const float4 hv = *(const float4*)&HT[bl][mm][k0];   // broadcast
            const float wj[12] = {w0.x,w0.y,w0.z,w0.w, w1.x,w1.y,w1.z,w1.w,
                                  w2.x,w2.y,w2.z,w2.w};
            const float hr4[4] = {hv.x, hv.y, hv.z, hv.w};
            #pragma unroll
            for (int r = 0; r < 4; ++r)
                #pragma unroll
                for (int j = 0; j < 12; ++j)
                    acc[r][j] = fmaf(hr4[r], wj[j], acc[r][j]);
        }
        __builtin_amdgcn_s_setprio(0);

        // ---- write-key dot ww[r][p] = sum_f w_write[t][m_][f] * h_read[k][f]
        float ww[4][4];
        #pragma unroll
        for (int r = 0; r < 4; ++r)
            #pragma unroll
            for (int p = 0; p < 4; ++p) ww[r][p] = 0.f;
        #pragma unroll 4
        for (int f = 0; f < 16; ++f) {
            const float4 wt4 = WWT4[f][half * 32 + m_];           // b128 spread
            const float4 hka = *(const float4*)&HR2T[bl][f][k0];  // broadcast
            const float wt[4] = {wt4.x, wt4.y, wt4.z, wt4.w};
            const float hk[4] = {hka.x, hka.y, hka.z, hka.w};
            #pragma unroll
            for (int r = 0; r < 4; ++r)
                #pragma unroll
                for (int p = 0; p < 4; ++p)
                    ww[r][p] = fmaf(hk[r], wt[p], ww[r][p]);
        }

        // ---- per-k epilogue: gates, packed logit reduce, argmax, gather
        #pragma unroll
        for (int r = 0; r < 4; ++r) {
            const int k = k0 + r;
            const float h2v = HT[bl][m_][k];
            float hn[4], part[4];
            #pragma unroll
            for (int p = 0; p < 4; ++p) {
                const float xr = gi_r[p][0] + acc[r][p*3+0];
                const float xz = gi_r[p][1] + acc[r][p*3+1];
                const float gn = bhn[p]     + acc[r][p*3+2];
                const float rg = 1.f / (1.f + __expf(-xr));
                const float zg = 1.f / (1.f + __expf(-xz));
                const float xn = gi_r[p][2] + rg * gn;
                const float e2 = __expf(2.f * xn);
                const float tn = 1.f - 2.f / (e2 + 1.f);   // tanh
                const float hv2 = (1.f - zg) * tn + zg * h2v;
                hn[p] = hv2;
                part[p] = hv2 * ww[r][p];                  // logit partial
            }
            // packed butterfly over m: p-low -> lane bit4, p-high -> lane bit3
            #pragma unroll
            for (int p = 0; p < 4; ++p)
                part[p] += __shfl_xor(part[p], 16, 64);
            const bool b4 = (lane & 16) != 0, b3 = (lane & 8) != 0;
            float v01 = b4 ? part[1] : part[0];
            float v23 = b4 ? part[3] : part[2];
            v01 += __shfl_xor(v01, 8, 64);
            v23 += __shfl_xor(v23, 8, 64);
            float v = b3 ? v23 : v01;
            v += __shfl_xor(v, 4, 64);
            v += __shfl_xor(v, 2, 64);
            v += __shfl_xor(v, 1, 64);
            if ((lane & 7) == 0) {       // 8 lanes: one per (p,half) = t
                const int p_ = ((lane >> 4) & 1) | (((lane >> 3) & 1) << 1);
                LG[bl][k][2 * p_ + half] = v;
            }
            // same-wave DS ordering: LG[k][0..7] complete for this wave's k
            const float4 l0 = *(const float4*)&LG[bl][k][0];   // broadcast
            const float4 l1 = *(const float4*)&LG[bl][k][4];
            const float* gp = gumb + ((size_t)b * NB_K + k) * NB_T;
            const float4 ga = *(const float4*)gp;
            const float4 gb = *(const float4*)(gp + 4);
            const float s[8] = {l0.x+ga.x, l0.y+ga.y, l0.z+ga.z, l0.w+ga.w,
                                l1.x+gb.x, l1.y+gb.y, l1.z+gb.z, l1.w+gb.w};
            float best = s[0]; int bt = 0;
            #pragma unroll
            for (int t2 = 1; t2 < 8; ++t2)
                if (s[t2] > best) { best = s[t2]; bt = t2; }   // first-max
            const int pstar = bt >> 1, hstar = bt & 1;
            float hsel = hn[0];
            hsel = (pstar == 1) ? hn[1] : hsel;
            hsel = (pstar == 2) ? hn[2] : hsel;
            hsel = (pstar == 3) ? hn[3] : hsel;
            if (half == hstar)
                out[(size_t)b * NB_NHID + k * 32 + m_] = hsel;
            if (lane < 8)
                out[H_OUT_ELEMS + ((size_t)b * NB_K + k) * NB_T + lane] =
                    (lane == bt) ? 1.f : 0.f;
        }
    }
}

extern "C" void kernel_launch(void* const* d_in, const int* in_sizes, int n_in,
                              void* d_out, int out_size, void* d_ws, size_t ws_size,
                              hipStream_t stream) {
    const float* x      = (const float*)d_in[0];
    const float* h      = (const float*)d_in[1];
    const float* Wih    = (const float*)d_in[2];
    const float* Whh    = (const float*)d_in[3];
    const float* bih    = (const float*)d_in[4];
    const float* bhh    = (const float*)d_in[5];
    const float* wread  = (const float*)d_in[6];
    const float* wwrite = (const float*)d_in[7];
    const float* gumb   = (const float*)d_in[8];
    float* out = (float*)d_out;
    float* gi  = (float*)d_ws;   // 2048*768*4 = 6 MB scratch

    k1_gemm_gi<<<dim3(32, 8), 1024, 0, stream>>>(x, Wih, bih, bhh, gi);
    k2_fused<<<dim3(256), 1024, 0, stream>>>(h, Whh, bhh, wread, wwrite,
                                             gumb, gi, out);
}

// Round 14
// 78.602 us; speedup vs baseline: 1.1354x; 1.1354x over previous
//
#include <hip/hip_runtime.h>

#define NB_BS   2048
#define NB_NINP 512
#define NB_NHID 512
#define NB_K    16
#define NB_T    8
#define NB_M    32
#define NB_C    768   // T * 3 * M
#define H_OUT_ELEMS (NB_BS * NB_NHID)   // 1048576

// ---------------------------------------------------------------------------
// Kernel 1 (r11 -- best measured total): 64x96 tile, 1024 threads,
// K-SPLIT-4 inside the block (kg = tid>>8 owns K-quarter), 4x6 micro with
// 4-addr broadcast av + conflict-free 3x b64 wv. Grid (32,8) = 256 = 1/CU.
// Partials combine through one reused ACCX buffer, 3 rounds.
// ---------------------------------------------------------------------------
__global__ __launch_bounds__(1024)
void k1_gemm_gi(const float* __restrict__ x, const float* __restrict__ Wih,
                const float* __restrict__ bih, const float* __restrict__ bhh,
                float* __restrict__ gi)
{
    __shared__ __align__(16) float As[4][16][68];    // [kg][k][row] 17.4 KB
    __shared__ __align__(16) float Bs[4][16][100];   // [kg][k][col] 25.6 KB
    __shared__ float ACCX[256][25];                  // 25.6 KB (25 coprime 32)

    const int tid  = threadIdx.x;
    const int kg   = tid >> 8;            // K-quarter
    const int ttid = tid & 255;
    const int row0 = blockIdx.x * 64;
    const int col0 = blockIdx.y * 96;
    const int rg   = ttid >> 4;           // 0..15 -> rows rg*4..+3 (4/wave)
    const int cg   = ttid & 15;           // 0..15 -> cols cg*6..+5
    const int kb0  = kg * 128;

    const int ar = ttid >> 2, akq = (ttid & 3) * 4;
    const int bc0 = ttid >> 2,         bk0 = (ttid & 3) * 4;
    const int bc1 = (256 + ttid) >> 2, bk1 = (ttid & 3) * 4;   // ttid<128 only

    float4 a0 = *(const float4*)&x[(size_t)(row0 + ar) * NB_NINP + kb0 + akq];
    float4 b0 = *(const float4*)&Wih[(size_t)(col0 + bc0) * NB_NINP + kb0 + bk0];
    float4 b1;
    if (ttid < 128)
        b1 = *(const float4*)&Wih[(size_t)(col0 + bc1) * NB_NINP + kb0 + bk1];

    float acc[4][6];
    #pragma unroll
    for (int i = 0; i < 4; ++i)
        #pragma unroll
        for (int e = 0; e < 6; ++e) acc[i][e] = 0.f;

    for (int slab = 0; slab < 8; ++slab) {           // 8 slabs of BK=16
        __syncthreads();
        As[kg][akq+0][ar]=a0.x; As[kg][akq+1][ar]=a0.y;
        As[kg][akq+2][ar]=a0.z; As[kg][akq+3][ar]=a0.w;
        Bs[kg][bk0+0][bc0]=b0.x; Bs[kg][bk0+1][bc0]=b0.y;
        Bs[kg][bk0+2][bc0]=b0.z; Bs[kg][bk0+3][bc0]=b0.w;
        if (ttid < 128) {
            Bs[kg][bk1+0][bc1]=b1.x; Bs[kg][bk1+1][bc1]=b1.y;
            Bs[kg][bk1+2][bc1]=b1.z; Bs[kg][bk1+3][bc1]=b1.w;
        }
        __syncthreads();
        if (slab < 7) {   // prefetch next slab of this K-quarter
            const int kb = kb0 + (slab + 1) * 16;
            a0 = *(const float4*)&x[(size_t)(row0 + ar) * NB_NINP + kb + akq];
            b0 = *(const float4*)&Wih[(size_t)(col0 + bc0) * NB_NINP + kb + bk0];
            if (ttid < 128)
                b1 = *(const float4*)&Wih[(size_t)(col0 + bc1) * NB_NINP + kb + bk1];
        }
        #pragma unroll
        for (int kk = 0; kk < 16; ++kk) {
            const float4 av = *(const float4*)&As[kg][kk][rg * 4];   // 4-addr bc
            const float2 w0 = *(const float2*)&Bs[kg][kk][cg * 6];
            const float2 w1 = *(const float2*)&Bs[kg][kk][cg * 6 + 2];
            const float2 w2 = *(const float2*)&Bs[kg][kk][cg * 6 + 4];
            const float avv[4] = {av.x, av.y, av.z, av.w};
            const float wvv[6] = {w0.x, w0.y, w1.x, w1.y, w2.x, w2.y};
            #pragma unroll
            for (int i = 0; i < 4; ++i)
                #pragma unroll
                for (int e = 0; e < 6; ++e)
                    acc[i][e] = fmaf(avv[i], wvv[e], acc[i][e]);
        }
    }

    #pragma unroll 1
    for (int src = 1; src < 4; ++src) {
        __syncthreads();
        if (kg == src) {
            #pragma unroll
            for (int i = 0; i < 4; ++i)
                #pragma unroll
                for (int e = 0; e < 6; ++e) ACCX[ttid][i * 6 + e] = acc[i][e];
        }
        __syncthreads();
        if (kg == 0) {
            #pragma unroll
            for (int i = 0; i < 4; ++i)
                #pragma unroll
                for (int e = 0; e < 6; ++e) acc[i][e] += ACCX[ttid][i * 6 + e];
        }
    }
    if (kg == 0) {                        // bias + store
        float bias[6];
        #pragma unroll
        for (int e = 0; e < 6; ++e) {
            const int cl = cg * 6 + e;    // c % 96
            const int c  = col0 + cl;
            bias[e] = bih[c] + (cl < 64 ? bhh[c] : 0.f);
        }
        #pragma unroll
        for (int i = 0; i < 4; ++i) {
            const size_t base = (size_t)(row0 + rg * 4 + i) * NB_C + col0 + cg * 6;
            #pragma unroll
            for (int e = 0; e < 6; e += 2) {
                float2 o;
                o.x = acc[i][e]   + bias[e];
                o.y = acc[i][e+1] + bias[e+1];
                *(float2*)&gi[base + e] = o;
            }
        }
    }
}

// ---------------------------------------------------------------------------
// Kernel 2 (r11 -- best measured: 50.4us / 60 VGPR / no spill): 256 x 1024
// thr (16 waves = 4 waves/SIMD), waves_per_eu(4,4) spill guard, wave (bl,kh),
// 2 passes of 4 k's, acc[4][12], setprio around the FMA cluster, packed-
// butterfly logit reduce + wave-local LG exchange. Staging = COALESCED global
// loads + 4-way-conflicted LDS scatter (r13 proved the conflict-free variant
// costs more in uncoalesced gather than it saves in banks).
// ---------------------------------------------------------------------------
__global__ __launch_bounds__(1024)
__attribute__((amdgpu_waves_per_eu(4, 4)))
void k2_fused(const float* __restrict__ h,      const float* __restrict__ Whh,
              const float* __restrict__ bhh,    const float* __restrict__ wread,
              const float* __restrict__ wwrite, const float* __restrict__ gumb,
              const float* __restrict__ gi,     float* __restrict__ out)
{
    __shared__ __align__(16) float4 P[3][32][64];   // 98304 B  W_hh planes
    __shared__ __align__(16) float4 WWT4[16][64];   // 16384 B  [f][half*32+m]:p-quad
    __shared__ __align__(16) float WR[512];         //  2048 B  w_read [m][f]
    __shared__ __align__(16) float HT[8][32][20];   // 20480 B  [bl][m][k]
    __shared__ __align__(16) float HR2T[8][16][20]; // 10240 B  [bl][f][k]
    __shared__ __align__(16) float LG[8][16][8];    //  4096 B  [bl][k][t]

    const int tid  = threadIdx.x;
    const int wave = tid >> 6, lane = tid & 63;
    const int bl   = wave >> 1, kh = wave & 1;
    const int b    = blockIdx.x * 8 + bl;
    const int m_   = lane & 31, half = lane >> 5;

    float* PF = (float*)P;
    for (int i = tid; i < 24576; i += 1024) {       // Whh flat [c][m]
        const int c = i >> 5, mm = i & 31;
        const int t = c / 96, rem = c - t * 96;
        const int gc = rem >> 5, mout = rem & 31;
        const int j  = (t >> 1) * 3 + gc;
        const int sl = ((t & 1) * 32 + mout) ^ (mm & 7);
        PF[(((j >> 2) * 32 + mm) * 64 + sl) * 4 + (j & 3)] = Whh[i];
    }
    for (int i = tid; i < 4096; i += 1024) {        // wwrite flat [t][m][f]
        const int t = i >> 9, mo = (i >> 4) & 31, f = i & 15;
        ((float*)WWT4)[(f * 64 + (t & 1) * 32 + mo) * 4 + (t >> 1)] = wwrite[i];
    }
    if (tid < 512) WR[tid] = wread[tid];
    #pragma unroll
    for (int e = 0; e < 4; ++e) {                   // this wave's h half-row, transposed
        const int idx = kh * 256 + e * 64 + lane;
        HT[bl][idx & 31][idx >> 5] = h[(size_t)b * NB_NHID + idx];
    }
    __syncthreads();   // only barrier; everything below is wave-local

    // ---- h_read for this wave's 8 k's: lane owns (k = kh*8 + lane>>3, f-pair)
    {
        const int kq = kh * 8 + (lane >> 3);
        const int f0 = (lane & 7) * 2;
        float s0 = 0.f, s1 = 0.f;
        #pragma unroll 8
        for (int mm = 0; mm < 32; ++mm) {
            const float hv = HT[bl][mm][kq];
            s0 = fmaf(hv, WR[mm * 16 + f0], s0);
            s1 = fmaf(hv, WR[mm * 16 + f0 + 1], s1);
        }
        HR2T[bl][f0    ][kq] = s0;
        HR2T[bl][f0 + 1][kq] = s1;
    }

    // ---- per-lane gi' (bih+bhh_{r,z} folded by k1) and bhh_n
    float gi_r[4][3], bhn[4];
    #pragma unroll
    for (int p = 0; p < 4; ++p) {
        const int t = 2 * p + half;
        #pragma unroll
        for (int gc = 0; gc < 3; ++gc)
            gi_r[p][gc] = gi[(size_t)b * NB_C + t * 96 + gc * 32 + m_];
        bhn[p] = bhh[t * 96 + 64 + m_];
    }

    #pragma unroll 1
    for (int pass = 0; pass < 2; ++pass) {
        const int k0 = kh * 8 + pass * 4;

        // ---- gh GEMM, 4 k's: 48 FMA per mm; 3 spread b128 + 1 broadcast b128
        float acc[4][12];
        #pragma unroll
        for (int r = 0; r < 4; ++r)
            #pragma unroll
            for (int j = 0; j < 12; ++j) acc[r][j] = 0.f;

        __builtin_amdgcn_s_setprio(1);
        #pragma unroll 4
        for (int mm = 0; mm < 32; ++mm) {
            const int sw = lane ^ (mm & 7);          // undo staging swizzle
            const float4 w0 = P[0][mm][sw];
            const float4 w1 = P[1][mm][sw];
            const float4 w2 = P[2][mm][sw];
            const float4 hv = *(const float4*)&HT[bl][mm][k0];   // broadcast
            const float wj[12] = {w0.x,w0.y,w0.z,w0.w, w1.x,w1.y,w1.z,w1.w,
                                  w2.x,w2.y,w2.z,w2.w};
            const float hr4[4] = {hv.x, hv.y, hv.z, hv.w};
            #pragma unroll
            for (int r = 0; r < 4; ++r)
                #pragma unroll
                for (int j = 0; j < 12; ++j)
                    acc[r][j] = fmaf(hr4[r], wj[j], acc[r][j]);
        }
        __builtin_amdgcn_s_setprio(0);

        // ---- write-key dot ww[r][p] = sum_f w_write[t][m_][f] * h_read[k][f]
        float ww[4][4];
        #pragma unroll
        for (int r = 0; r < 4; ++r)
            #pragma unroll
            for (int p = 0; p < 4; ++p) ww[r][p] = 0.f;
        #pragma unroll 4
        for (int f = 0; f < 16; ++f) {
            const float4 wt4 = WWT4[f][half * 32 + m_];           // b128 spread
            const float4 hka = *(const float4*)&HR2T[bl][f][k0];  // broadcast
            const float wt[4] = {wt4.x, wt4.y, wt4.z, wt4.w};
            const float hk[4] = {hka.x, hka.y, hka.z, hka.w};
            #pragma unroll
            for (int r = 0; r < 4; ++r)
                #pragma unroll
                for (int p = 0; p < 4; ++p)
                    ww[r][p] = fmaf(hk[r], wt[p], ww[r][p]);
        }

        // ---- per-k epilogue: gates, packed logit reduce, argmax, gather
        #pragma unroll
        for (int r = 0; r < 4; ++r) {
            const int k = k0 + r;
            const float h2v = HT[bl][m_][k];
            float hn[4], part[4];
            #pragma unroll
            for (int p = 0; p < 4; ++p) {
                const float xr = gi_r[p][0] + acc[r][p*3+0];
                const float xz = gi_r[p][1] + acc[r][p*3+1];
                const float gn = bhn[p]     + acc[r][p*3+2];
                const float rg = 1.f / (1.f + __expf(-xr));
                const float zg = 1.f / (1.f + __expf(-xz));
                const float xn = gi_r[p][2] + rg * gn;
                const float e2 = __expf(2.f * xn);
                const float tn = 1.f - 2.f / (e2 + 1.f);   // tanh
                const float hv2 = (1.f - zg) * tn + zg * h2v;
                hn[p] = hv2;
                part[p] = hv2 * ww[r][p];                  // logit partial
            }
            // packed butterfly over m: p-low -> lane bit4, p-high -> lane bit3
            #pragma unroll
            for (int p = 0; p < 4; ++p)
                part[p] += __shfl_xor(part[p], 16, 64);
            const bool b4 = (lane & 16) != 0, b3 = (lane & 8) != 0;
            float v01 = b4 ? part[1] : part[0];
            float v23 = b4 ? part[3] : part[2];
            v01 += __shfl_xor(v01, 8, 64);
            v23 += __shfl_xor(v23, 8, 64);
            float v = b3 ? v23 : v01;
            v += __shfl_xor(v, 4, 64);
            v += __shfl_xor(v, 2, 64);
            v += __shfl_xor(v, 1, 64);
            if ((lane & 7) == 0) {       // 8 lanes: one per (p,half) = t
                const int p_ = ((lane >> 4) & 1) | (((lane >> 3) & 1) << 1);
                LG[bl][k][2 * p_ + half] = v;
            }
            // same-wave DS ordering: LG[k][0..7] complete for this wave's k
            const float4 l0 = *(const float4*)&LG[bl][k][0];   // broadcast
            const float4 l1 = *(const float4*)&LG[bl][k][4];
            const float* gp = gumb + ((size_t)b * NB_K + k) * NB_T;
            const float4 ga = *(const float4*)gp;
            const float4 gb = *(const float4*)(gp + 4);
            const float s[8] = {l0.x+ga.x, l0.y+ga.y, l0.z+ga.z, l0.w+ga.w,
                                l1.x+gb.x, l1.y+gb.y, l1.z+gb.z, l1.w+gb.w};
            float best = s[0]; int bt = 0;
            #pragma unroll
            for (int t2 = 1; t2 < 8; ++t2)
                if (s[t2] > best) { best = s[t2]; bt = t2; }   // first-max
            const int pstar = bt >> 1, hstar = bt & 1;
            float hsel = hn[0];
            hsel = (pstar == 1) ? hn[1] : hsel;
            hsel = (pstar == 2) ? hn[2] : hsel;
            hsel = (pstar == 3) ? hn[3] : hsel;
            if (half == hstar)
                out[(size_t)b * NB_NHID + k * 32 + m_] = hsel;
            if (lane < 8)
                out[H_OUT_ELEMS + ((size_t)b * NB_K + k) * NB_T + lane] =
                    (lane == bt) ? 1.f : 0.f;
        }
    }
}

extern "C" void kernel_launch(void* const* d_in, const int* in_sizes, int n_in,
                              void* d_out, int out_size, void* d_ws, size_t ws_size,
                              hipStream_t stream) {
    const float* x      = (const float*)d_in[0];
    const float* h      = (const float*)d_in[1];
    const float* Wih    = (const float*)d_in[2];
    const float* Whh    = (const float*)d_in[3];
    const float* bih    = (const float*)d_in[4];
    const float* bhh    = (const float*)d_in[5];
    const float* wread  = (const float*)d_in[6];
    const float* wwrite = (const float*)d_in[7];
    const float* gumb   = (const float*)d_in[8];
    float* out = (float*)d_out;
    float* gi  = (float*)d_ws;   // 2048*768*4 = 6 MB scratch

    k1_gemm_gi<<<dim3(32, 8), 1024, 0, stream>>>(x, Wih, bih, bhh, gi);
    k2_fused<<<dim3(256), 1024, 0, stream>>>(h, Whh, bhh, wread, wwrite,
                                             gumb, gi, out);
}